// Round 8
// baseline (290.087 us; speedup 1.0000x reference)
//
#include <hip/hip_runtime.h>

// Problem dims (fixed by the reference): B=256, T=100, D=1024, H=128, C=5
constexpr int Bsz = 256;
constexpr int Tn  = 100;
constexpr int Dn  = 1024;
constexpr int Hn  = 128;
constexpr int Cn  = 5;

// float64 values of np.exp(-1/10), np.exp(-1/20)
#define D1 0.9048374180359595731642491
#define D2 0.9512294245007140090914253

typedef double double4_t __attribute__((ext_vector_type(4)));

// ---------------------------------------------------------------------------
// R16 == R15 resubmitted verbatim (R15's bench was an infra failure —
// "container failed twice" — never evaluated; same signature as Round 2,
// which resolved on resubmission). Audit found no OOB/hang: persistent
// loop exits uniformly, no inter-block waits (no co-residency needed),
// ticket memset-covered, bounded atomic count.
//
// R15 theory under test (vs R14: 272.1us total, gemm 134.5us @ MfmaUtil 64):
// persistent-block work-stealing gemm. Gemm ideal MFMA content = 85.3us;
// loss = scheduling 78% (3200 blocks on 1024 resident slots = 3.125
// cohorts, last cohort 128 blocks on 256 CUs) x per-block stalls ~0.81.
// Fix the scheduling term: launch exactly 1024 blocks (4/CU, LDS-bound
// residency); each grabs tiles from a global atomic ticket (zeroed by the
// existing memset). Balance granularity drops from one cohort (~43us) to
// one tile (~6.8us CU-share) -> ~95% sched eff, robust to undefined
// dispatch order. Pre-grab __syncthreads doubles as the LDS-reuse guard.
// Inner loop, LDS layout, KSPL=4 atomic epilogue, D-probe: unchanged.
// ---------------------------------------------------------------------------
constexpr int TILE_M = 32;
constexpr int KSPL   = 4;
constexpr int KH     = Dn / KSPL;     // 256 k per block
constexpr int SC     = 128;           // staging sub-chunk (k)
constexpr int NS     = KH / SC;       // 2
constexpr int KPAD   = 132;           // 128 k + 4 pad (f32)
constexpr int NTILES = (Bsz * Tn / TILE_M) * KSPL;   // 3200
constexpr int GRIDP  = 1024;          // persistent blocks = resident slots

__global__ __launch_bounds__(256) void gemm_mfma_f64(
    const float* __restrict__ X, const float* __restrict__ W1,
    double* __restrict__ Hc, unsigned int* __restrict__ ticket)
{
  // As[buf][m][k] : 2 * 32 * 132 * 4 = 33792 B  -> 4 blocks/CU resident
  __shared__ __align__(16) float As[2][TILE_M][KPAD];
  __shared__ unsigned int tileS;

  const int tid  = threadIdx.x;

  // tile-independent thread decomposition (hoisted)
  const int rA = tid >> 3;            // staging: A row 0..31
  const int c8 = tid & 7;             // staging: float4 k-group
  const int w    = tid >> 6;          // compute: wave -> n-tiles {w*16, w*16+64}
  const int lane = tid & 63;
  const int mA   = lane & 15;
  const int kq   = lane >> 4;
  const int n0   = w * 16;

  // --- D-layout probe: D[i][j] = 16*i + j (hoisted, tile-independent) ---
  int drow[4], dcol[4];
  {
    const double ap  = (kq == 0) ? (double)(16 * mA) : (kq == 1 ? 1.0 : 0.0);
    const double bpv = (kq == 0) ? 1.0 : (kq == 1 ? (double)mA : 0.0);
    double4_t pz = {0.0, 0.0, 0.0, 0.0};
    pz = __builtin_amdgcn_mfma_f64_16x16x4f64(ap, bpv, pz, 0, 0, 0);
    #pragma unroll
    for (int r = 0; r < 4; ++r) {
      const int p = (int)pz[r];
      drow[r] = p >> 4;
      dcol[r] = p & 15;
    }
  }

  while (true) {
    // all threads done reading LDS of the previous tile before re-grab
    __syncthreads();
    if (tid == 0)
      tileS = __hip_atomic_fetch_add(ticket, 1u, __ATOMIC_RELAXED,
                                     __HIP_MEMORY_SCOPE_AGENT);
    __syncthreads();
    const unsigned int tile = tileS;
    if (tile >= NTILES) break;        // uniform exit

    const int mt    = tile >> 2;
    const int kspl  = tile & 3;
    const int m0    = mt * TILE_M;
    const int kbase = kspl * KH;

    // staging source: row rc of the [B*T, D] activation matrix
    // (t0=0, Tc=Tn -> global row == rc directly)
    const int rc = m0 + rA;
    const float* Apt = X + (size_t)rc * Dn + kbase;

    double4_t acc00 = {0.0, 0.0, 0.0, 0.0};  // m-sub 0, n-tile 0
    double4_t acc01 = {0.0, 0.0, 0.0, 0.0};  // m-sub 0, n-tile 1
    double4_t acc10 = {0.0, 0.0, 0.0, 0.0};  // m-sub 1, n-tile 0
    double4_t acc11 = {0.0, 0.0, 0.0, 0.0};  // m-sub 1, n-tile 1

    // prefetch sub-chunk 0: 4 float4 per thread (32 m x 128 k / 256 thr)
    float4 pf[4];
    #pragma unroll
    for (int j = 0; j < 4; ++j)
      pf[j] = *(const float4*)(Apt + 4 * (c8 + j * 8));

    int buf = 0;
    for (int s = 0; s < NS; ++s) {
      // staged registers -> LDS ([m][k] layout), one ds_write_b128 each
      #pragma unroll
      for (int j = 0; j < 4; ++j)
        *(float4*)&As[buf][rA][4 * (c8 + j * 8)] = pf[j];
      __syncthreads();

      // prefetch sub-chunk s+1 (overlaps compute below)
      if (s + 1 < NS) {
        #pragma unroll
        for (int j = 0; j < 4; ++j)
          pf[j] = *(const float4*)(Apt + (s + 1) * SC + 4 * (c8 + j * 8));
      }

      // B read as f32 directly from W1, converted in-loop (exact)
      const float* bp = W1 + (size_t)(kbase + s * SC + kq) * Hn + n0 + mA;

      // ---- software-pipelined K loop: NK=32 steps of 4 k each -----------
      constexpr int NK = SC / 4;      // 32
      double a0r[2], a1r[2];          // LDS a, depth-2 rolling
      double b0r[4], b1r[4];          // L2  b, depth-4 rolling

      a0r[0] = (double)As[buf][mA][kq];
      a1r[0] = (double)As[buf][16 + mA][kq];
      #pragma unroll
      for (int i = 0; i < 3; ++i) {
        b0r[i] = (double)bp[(size_t)(4 * i) * Hn];
        b1r[i] = (double)bp[(size_t)(4 * i) * Hn + 64];
      }

      #pragma unroll
      for (int i = 0; i < NK; ++i) {
        if (i + 1 < NK) {             // a for iter i+1
          a0r[(i + 1) & 1] = (double)As[buf][mA][4 * (i + 1) + kq];
          a1r[(i + 1) & 1] = (double)As[buf][16 + mA][4 * (i + 1) + kq];
        }
        if (i + 3 < NK) {             // b for iter i+3
          b0r[(i + 3) & 3] = (double)bp[(size_t)(4 * (i + 3)) * Hn];
          b1r[(i + 3) & 3] = (double)bp[(size_t)(4 * (i + 3)) * Hn + 64];
        }
        const double a0 = a0r[i & 1];
        const double a1 = a1r[i & 1];
        const double b0 = b0r[i & 3];
        const double b1 = b1r[i & 3];
        acc00 = __builtin_amdgcn_mfma_f64_16x16x4f64(a0, b0, acc00, 0, 0, 0);
        acc01 = __builtin_amdgcn_mfma_f64_16x16x4f64(a0, b1, acc01, 0, 0, 0);
        acc10 = __builtin_amdgcn_mfma_f64_16x16x4f64(a1, b0, acc10, 0, 0, 0);
        acc11 = __builtin_amdgcn_mfma_f64_16x16x4f64(a1, b1, acc11, 0, 0, 0);
      }
      buf ^= 1;
    }

    // epilogue: atomic-add partial K-quarter into Hc (memset-zeroed base)
    #pragma unroll
    for (int r = 0; r < 4; ++r) {
      double* e00 = &Hc[(size_t)(m0 + drow[r]) * Hn + n0 + dcol[r]];
      double* e01 = &Hc[(size_t)(m0 + drow[r]) * Hn + n0 + 64 + dcol[r]];
      double* e10 = &Hc[(size_t)(m0 + 16 + drow[r]) * Hn + n0 + dcol[r]];
      double* e11 = &Hc[(size_t)(m0 + 16 + drow[r]) * Hn + n0 + 64 + dcol[r]];
      __hip_atomic_fetch_add(e00, acc00[r], __ATOMIC_RELAXED, __HIP_MEMORY_SCOPE_AGENT);
      __hip_atomic_fetch_add(e01, acc01[r], __ATOMIC_RELAXED, __HIP_MEMORY_SCOPE_AGENT);
      __hip_atomic_fetch_add(e10, acc10[r], __ATOMIC_RELAXED, __HIP_MEMORY_SCOPE_AGENT);
      __hip_atomic_fetch_add(e11, acc11[r], __ATOMIC_RELAXED, __HIP_MEMORY_SCOPE_AGENT);
    }
  }
}

// ---------------------------------------------------------------------------
// Phase 2 scan v3 — UNCHANGED from R14. Full T=100 in one dispatch, Hc
// staged in two 50-step halves; ballot spike masks, parallel (t,c) dot
// products, 5-thread v2 chains. LDS 61920 B.
// ---------------------------------------------------------------------------
constexpr int THALF = 50;

__global__ __launch_bounds__(256) void snn_scan_v3(
    const double* __restrict__ Hc, const float* __restrict__ b1,
    const float* __restrict__ W2, const float* __restrict__ b2,
    float* __restrict__ out)
{
#pragma clang fp contract(off)
  __shared__ __align__(16) double HcL[THALF * Hn];        // 51200 B
  __shared__ double W2d[Hn * Cn];                          // 5120 B
  __shared__ double Pp[Tn * Cn];                           // 4000 B
  __shared__ unsigned long long Mk[Tn][2];                 // 1600 B

  const int b   = blockIdx.x;
  const int tid = threadIdx.x;

  // W2 (f32->f64) into LDS once
  for (int i = tid; i < Hn * Cn; i += 256)
    W2d[i] = (double)W2[i];

  // layer-1 per-lane constants (j0 safe for all threads; only wave0 uses)
  const int j0 = (tid & 63) * 2;
  const double b1a = (double)b1[j0];
  const double b1b = (double)b1[j0 + 1];
  double v1a = 0.0, v1b = 0.0;                  // t0 == 0 always (Tc = Tn)

  const double* hsrc = Hc + (size_t)b * Tn * Hn;

  for (int h = 0; h < 2; ++h) {
    if (h) __syncthreads();                     // P1(h-1) done before restage

    // ---- stage half h of Hc into LDS (all 256 threads) -------------------
    {
      const double* src = hsrc + (size_t)h * THALF * Hn;
      const int nd2 = THALF * (Hn / 2);         // 3200 double2
      int i = tid;
      for (; i + 3 * 256 < nd2; i += 4 * 256) { // 4-deep load pipeline
        double2 a0 = *(const double2*)(src + 2 * (i + 0 * 256));
        double2 a1 = *(const double2*)(src + 2 * (i + 1 * 256));
        double2 a2 = *(const double2*)(src + 2 * (i + 2 * 256));
        double2 a3 = *(const double2*)(src + 2 * (i + 3 * 256));
        *(double2*)&HcL[2 * (i + 0 * 256)] = a0;
        *(double2*)&HcL[2 * (i + 1 * 256)] = a1;
        *(double2*)&HcL[2 * (i + 2 * 256)] = a2;
        *(double2*)&HcL[2 * (i + 3 * 256)] = a3;
      }
      for (; i < nd2; i += 256)
        *(double2*)&HcL[2 * i] = *(const double2*)(src + 2 * i);
    }
    __syncthreads();

    // ---- P1: wave 0 runs the layer-1 LIF chain for this half --------------
    if (tid < 64) {
      const int lane = tid;
      double2 hnext = *(const double2*)&HcL[j0];
      for (int t = 0; t < THALF; ++t) {
        const double2 hc = hnext;
        const int tn = (t + 1 < THALF) ? (t + 1) : t;
        hnext = *(const double2*)&HcL[tn * Hn + j0];   // 1-ahead prefetch

        // v1 = (v1*d1 + h) + b1  (left-assoc, separate roundings)
        v1a = (v1a * D1 + hc.x) + b1a;
        v1b = (v1b * D1 + hc.y) + b1b;
        const bool ca = (v1a >= 1.0);
        const bool cb = (v1b >= 1.0);
        const unsigned long long mA = __ballot(ca);    // neuron 2L   <- bit L
        const unsigned long long mB = __ballot(cb);    // neuron 2L+1 <- bit L
        if (ca) v1a = 0.0;
        if (cb) v1b = 0.0;
        if (lane == 0) { Mk[h * THALF + t][0] = mA; Mk[h * THALF + t][1] = mB; }
      }
    }
  }
  __syncthreads();

  // ---- P2: all (t,c) classifier dot-products in parallel -------------------
  for (int pi = tid; pi < Tn * Cn; pi += 256) {
    const int tt = pi / Cn;
    const int cc = pi - tt * Cn;
    const unsigned long long mA = Mk[tt][0];
    const unsigned long long mB = Mk[tt][1];
    double sA = 0.0, sB = 0.0;
    #pragma unroll
    for (int L = 0; L < 64; ++L) {
      sA += ((mA >> L) & 1ull) ? W2d[(2 * L) * Cn + cc]     : 0.0;
      sB += ((mB >> L) & 1ull) ? W2d[(2 * L + 1) * Cn + cc] : 0.0;
    }
    Pp[pi] = sA + sB;
  }
  __syncthreads();

  // ---- P3: per-class v2/acc chains (5 independent threads) -----------------
  if (tid < Cn) {
    const int c = tid;
    const double bb2 = (double)b2[c];
    double v2 = 0.0, acc = 0.0;
    double pn = Pp[c];                                  // t = 0
    for (int t = 0; t < Tn; ++t) {
      const double p = pn;
      const int tn = (t + 1 < Tn) ? (t + 1) : t;
      pn = Pp[tn * Cn + c];                             // 1-ahead prefetch
      const double v = ((v2 * D2) + p) + bb2;           // unchanged order
      const bool s2 = (v >= 1.0);
      v2 = s2 ? 0.0 : v;
      acc += s2 ? 1.0 : 0.0;
    }
    out[(size_t)b * Cn + c] = (float)(acc / 100.0);
  }
}

// ---------------------------------------------------------------------------
extern "C" void kernel_launch(void* const* d_in, const int* in_sizes, int n_in,
                              void* d_out, int out_size, void* d_ws, size_t ws_size,
                              hipStream_t stream) {
  const float* X  = (const float*)d_in[0];   // [B,T,D]
  const float* W1 = (const float*)d_in[1];   // [D,H]
  const float* b1 = (const float*)d_in[2];   // [H]
  const float* W2 = (const float*)d_in[3];   // [H,C]
  const float* b2 = (const float*)d_in[4];   // [C]
  float* out = (float*)d_out;                // [B,C]

  // ws = Hc [B*Tn, H] f64 (26.2MB) | ticket (u32, memset-zeroed with Hc)
  double* Hc = (double*)d_ws;
  const size_t hcDoubles = (size_t)Bsz * Tn * Hn;
  const size_t hcBytes   = hcDoubles * sizeof(double);
  unsigned int* ticket = (unsigned int*)(Hc + hcDoubles);

  hipMemsetAsync(Hc, 0, hcBytes + 64, stream);       // Hc base + ticket = 0
  gemm_mfma_f64<<<dim3(GRIDP), dim3(256), 0, stream>>>(X, W1, Hc, ticket);
  snn_scan_v3<<<dim3(Bsz), dim3(256), 0, stream>>>(Hc, b1, W2, b2, out);
}